// Round 7
// baseline (311.290 us; speedup 1.0000x reference)
//
#include <hip/hip_runtime.h>

#define B_SZ 16
#define S_SZ 8192
#define H_SZ 256

typedef _Float16 half8 __attribute__((ext_vector_type(8)));
typedef float f32x4 __attribute__((ext_vector_type(4)));

__device__ __forceinline__ float tanh_fast(float x) {
  // tanh(x) = 1 - 2/(e^{2x}+1); saturates correctly at +-inf.
  float e = __expf(2.0f * x);
  return 1.0f - 2.0f / (e + 1.0f);
}

// Async global load: issues the load here; the destination registers are NOT
// valid until a matching s_waitcnt vmcnt(N). vmcnt retires in issue order.
__device__ __forceinline__ f32x4 gload4(const float* p) {
  f32x4 r;
  asm volatile("global_load_dwordx4 %0, %1, off" : "=v"(r) : "v"(p));
  return r;
}

// Counted vmem wait + scheduler fence (rule 18: VALU consumers of asm-load
// outputs must not be hoisted above the waitcnt).
#define WAITVM(N)                                          \
  do {                                                     \
    asm volatile("s_waitcnt vmcnt(" #N ")" ::: "memory");  \
    __builtin_amdgcn_sched_barrier(0);                     \
  } while (0)

// Barrier WITHOUT the vmcnt(0) drain __syncthreads() would emit: LDS-only
// visibility (lgkmcnt(0)) + s_barrier. Global loads stay in flight across it.
#define BAR_LDS()                                          \
  do {                                                     \
    asm volatile("s_waitcnt lgkmcnt(0)" ::: "memory");     \
    __builtin_amdgcn_s_barrier();                          \
    __builtin_amdgcn_sched_barrier(0);                     \
  } while (0)

// ---------------------------------------------------------------------------
// Phase A: qb[b,o] = dot(query[b,:], Wq[o,:]) + b_attn[o]  (qb -> ctx slot,
// consumed by fused kernel, overwritten by combine with final context).
// ---------------------------------------------------------------------------
__global__ __launch_bounds__(256) void prep_kernel(
    const float* __restrict__ query, const float* __restrict__ W_attn,
    const float* __restrict__ b_attn, float* __restrict__ qb) {
  const int b = blockIdx.x;
  const int jo = blockIdx.y;
  const int wid = threadIdx.x >> 6;
  const int lane = threadIdx.x & 63;
  const float4 q4 = *(const float4*)(query + b * H_SZ + lane * 4);
#pragma unroll 4
  for (int i = 0; i < 16; i++) {
    const int o = jo * 64 + wid * 16 + i;
    const float4 w = *(const float4*)(W_attn + (size_t)o * 512 + lane * 4);
    float p = q4.x * w.x + q4.y * w.y + q4.z * w.z + q4.w * w.w;
#pragma unroll
    for (int off = 32; off >= 1; off >>= 1) p += __shfl_xor(p, off, 64);
    if (lane == 0) qb[b * H_SZ + o] = p + b_attn[o];
  }
}

// ---------------------------------------------------------------------------
// Fused scores+softmax+context, v5. 512 blocks x 1024 threads (16 waves).
// v3b data layout + the anti-convoy schedule:
//  - in-loop barriers are lgkmcnt-only (BAR_LDS): no vmcnt(0) drain, so
//    global loads stay in flight across barriers (T4: never drain vmcnt
//    in the main loop). LDS dbuf/psum visibility is fully preserved.
//  - key (chunk c+1) and value (chunk c) loads are issued at chunk top as
//    asm global_load_dwordx4; key is waited with vmcnt(2) just before its
//    cvt+ds_write (the two key loads are the oldest outstanding), value
//    with vmcnt(0) just before the fold (a whole MFMA+softmax phase of
//    latency cover). Wave0's score store happens after the fold so no
//    wait ever includes a store ack.
// ---------------------------------------------------------------------------
__global__ __launch_bounds__(1024, 4) void fused_kernel(
    const float* __restrict__ key, const float* __restrict__ value,
    const float* __restrict__ W_attn, const float* __restrict__ qb,
    const float* __restrict__ vvec, float* __restrict__ scores,
    float* __restrict__ ctxp, float* __restrict__ mblk,
    float* __restrict__ zblk) {
  __shared__ __align__(16) _Float16 kbuf[2][32 * 256];  // 2 x 16 KiB staging
  __shared__ float psum[8][32];                         // per-chunk scores
  __shared__ float4 comb[16][64];                       // epilogue (16 KiB)

  const int tid = threadIdx.x;
  const int wid = tid >> 6;    // o-tile index, 0..15
  const int lane = tid & 63;
  const int n = lane & 15;     // A row (o within tile) / D column (key row)
  const int quad = lane >> 4;
  const int rowBase = blockIdx.x * 256;
  const int b = blockIdx.x >> 5;  // 32 blocks per batch

  // A fragments: Wk[o = wid*16 + n][k], k = ks*32 + quad*8 + j. Loaded once.
  half8 afrag[8];
  {
    const float* wrow = W_attn + (size_t)(wid * 16 + n) * 512 + 256 + quad * 8;
#pragma unroll
    for (int ks = 0; ks < 8; ks++) {
      float4 f0 = *(const float4*)(wrow + ks * 32);
      float4 f1 = *(const float4*)(wrow + ks * 32 + 4);
      half8 a;
      a[0] = (_Float16)f0.x; a[1] = (_Float16)f0.y;
      a[2] = (_Float16)f0.z; a[3] = (_Float16)f0.w;
      a[4] = (_Float16)f1.x; a[5] = (_Float16)f1.y;
      a[6] = (_Float16)f1.z; a[7] = (_Float16)f1.w;
      afrag[ks] = a;
    }
  }
  // Epilogue constants: this lane holds D rows m = quad*4+rg -> o = wid*16+m.
  float qbv[4], vvv[4];
#pragma unroll
  for (int rg = 0; rg < 4; rg++) {
    qbv[rg] = qb[b * H_SZ + wid * 16 + quad * 4 + rg];
    vvv[rg] = vvec[wid * 16 + quad * 4 + rg];
  }

  if (tid < 256) ((float*)psum)[tid] = 0.f;  // all 8 chunk buffers

  // Key staging: 1024 threads = 32 rows x 32 segs (8 f32 each), XOR-swizzled.
  const int srow = tid >> 5;
  const int sseg = tid & 31;
  const size_t sbase = (size_t)(rowBase + srow) * H_SZ + sseg * 8;
  const int sdst = srow * 256 + ((sseg ^ srow) << 3);

  // Value: wave w owns rows 2w, 2w+1 of each chunk; lane = float4 column.
  const float* vbase = value + (size_t)(rowBase + 2 * wid) * H_SZ + lane * 4;

  // Prologue: stage key chunk 0 (plain loads; compiler-managed waits).
  {
    float4 f0 = *(const float4*)(key + sbase);
    float4 f1 = *(const float4*)(key + sbase + 4);
    half8 h;
    h[0] = (_Float16)f0.x; h[1] = (_Float16)f0.y;
    h[2] = (_Float16)f0.z; h[3] = (_Float16)f0.w;
    h[4] = (_Float16)f1.x; h[5] = (_Float16)f1.y;
    h[6] = (_Float16)f1.z; h[7] = (_Float16)f1.w;
    *(half8*)&kbuf[0][sdst] = h;
  }
  BAR_LDS();

  float4 acc4 = {0.f, 0.f, 0.f, 0.f};  // this wave's value accumulator
  float m_run = -1e30f;                // redundant per-wave running max
  float z_run = 0.f;                   // meaningful only in wave 0

  for (int c = 0; c < 8; c++) {
    // Issue order matters for counted vmcnt: key first (oldest), value next.
    f32x4 k0, k1, v0, v1;
    if (c < 7) {
      const size_t nb = sbase + (size_t)(c + 1) * 32 * H_SZ;
      k0 = gload4(key + nb);
      k1 = gload4(key + nb + 4);
    }
    {
      const float* vp = vbase + (size_t)c * 32 * H_SZ;
      v0 = gload4(vp);
      v1 = gload4(vp + H_SZ);
    }
    __builtin_amdgcn_sched_barrier(0);  // pin issue point at chunk top

    const _Float16* kb = kbuf[c & 1];
#pragma unroll
    for (int rt = 0; rt < 2; rt++) {
      const int lrow = rt * 16 + n;  // key row within chunk (D column)
      f32x4 acc = {0.f, 0.f, 0.f, 0.f};
#pragma unroll
      for (int ks = 0; ks < 8; ks++) {
        half8 bfrag =
            *(const half8*)&kb[lrow * 256 + (((ks * 4 + quad) ^ lrow) << 3)];
        acc = __builtin_amdgcn_mfma_f32_16x16x32_f16(afrag[ks], bfrag, acc,
                                                     0, 0, 0);
      }
      float p = 0.f;
#pragma unroll
      for (int rg = 0; rg < 4; rg++)
        p = fmaf(vvv[rg], tanh_fast(qbv[rg] + acc[rg]), p);
      // Sum over the 4 quads (same key row, different o-subsets).
      p += __shfl_xor(p, 16, 64);
      p += __shfl_xor(p, 32, 64);
      if (quad == 0) atomicAdd(&psum[c][lrow], p);
    }
    if (c < 7) {  // key loads are the 2 oldest outstanding -> vmcnt(2)
      WAITVM(2);
      half8 h;
      h[0] = (_Float16)k0[0]; h[1] = (_Float16)k0[1];
      h[2] = (_Float16)k0[2]; h[3] = (_Float16)k0[3];
      h[4] = (_Float16)k1[0]; h[5] = (_Float16)k1[1];
      h[6] = (_Float16)k1[2]; h[7] = (_Float16)k1[3];
      *(half8*)&kbuf[(c + 1) & 1][sdst] = h;
    }
    BAR_LDS();  // psum[c] + kbuf[(c+1)&1] visible; value loads STILL in flight

    // Redundant per-wave online softmax (identical in every wave).
    const float sv = psum[c][lane & 31];
    float cm = sv;
#pragma unroll
    for (int off = 16; off >= 1; off >>= 1)
      cm = fmaxf(cm, __shfl_xor(cm, off, 64));
    const float m_new = fmaxf(m_run, cm);
    const float scl = __expf(m_run - m_new);  // 0 on first chunk
    m_run = m_new;
    const float wl = __expf(sv - m_new);
    // Weights for this wave's 2 value rows (broadcast from lanes 2w, 2w+1).
    const float w0 = __shfl(wl, 2 * wid + 0, 64);
    const float w1 = __shfl(wl, 2 * wid + 1, 64);

    WAITVM(0);  // value rows landed (issued a full chunk ago)
    acc4.x = fmaf(w1, v1[0], fmaf(w0, v0[0], acc4.x * scl));
    acc4.y = fmaf(w1, v1[1], fmaf(w0, v0[1], acc4.y * scl));
    acc4.z = fmaf(w1, v1[2], fmaf(w0, v0[2], acc4.z * scl));
    acc4.w = fmaf(w1, v1[3], fmaf(w0, v0[3], acc4.w * scl));

    if (wid == 0) {  // raw scores + running Z (after fold: store ack never
                     // sits inside a wait window)
      if (lane < 32) scores[rowBase + c * 32 + lane] = sv;
      float zc = wl;
#pragma unroll
      for (int off = 16; off >= 1; off >>= 1) zc += __shfl_xor(zc, off, 64);
      z_run = fmaf(z_run, scl, zc);
    }
  }

  // Epilogue: combine 16 wave accumulators; write per-block partials.
  comb[wid][lane] = acc4;
  BAR_LDS();
  if (tid < 64) {
    float4 t4 = comb[0][tid];
#pragma unroll
    for (int j = 1; j < 16; j++) {
      const float4 u = comb[j][tid];
      t4.x += u.x; t4.y += u.y; t4.z += u.z; t4.w += u.w;
    }
    *(float4*)(ctxp + (size_t)blockIdx.x * 256 + tid * 4) = t4;
  }
  if (tid == 0) {
    mblk[blockIdx.x] = m_run;
    zblk[blockIdx.x] = z_run;
  }
}

// ---------------------------------------------------------------------------
// Combine: per batch, merge the 32 block partials -> global m, Z, context;
// normalize the raw scores into attention weights in place. 16 blocks x 1024.
// ---------------------------------------------------------------------------
__global__ __launch_bounds__(1024) void combine_kernel(
    const float* __restrict__ ctxp, const float* __restrict__ mblk,
    const float* __restrict__ zblk, float* __restrict__ attn,
    float* __restrict__ ctx) {
  const int b = blockIdx.x;
  const int t = threadIdx.x;
  __shared__ float ms[32], zs[32];
  if (t < 32) {
    ms[t] = mblk[b * 32 + t];
    zs[t] = zblk[b * 32 + t];
  }
  __syncthreads();
  float m = -1e30f;
#pragma unroll
  for (int j = 0; j < 32; j++) m = fmaxf(m, ms[j]);
  float Z = 0.f;
  float e[32];  // fully unrolled -> registers (no scratch)
#pragma unroll
  for (int j = 0; j < 32; j++) {
    e[j] = __expf(ms[j] - m);
    Z = fmaf(zs[j], e[j], Z);
  }
  const float invZ = 1.0f / Z;
  if (t < 256) {
    float acc = 0.f;
#pragma unroll
    for (int j = 0; j < 32; j++)
      acc = fmaf(ctxp[(size_t)(b * 32 + j) * 256 + t], e[j], acc);
    ctx[b * H_SZ + t] = acc * invZ;
  }
  float* arow = attn + (size_t)b * S_SZ;
#pragma unroll
  for (int k = 0; k < 8; k++) {
    const int idx = k * 1024 + t;
    arow[idx] = __expf(arow[idx] - m) * invZ;
  }
}

// ---------------------------------------------------------------------------
extern "C" void kernel_launch(void* const* d_in, const int* in_sizes, int n_in,
                              void* d_out, int out_size, void* d_ws,
                              size_t ws_size, hipStream_t stream) {
  const float* query = (const float*)d_in[0];   // (16,1,256)
  const float* key = (const float*)d_in[1];     // (16,8192,256)
  const float* value = (const float*)d_in[2];   // (16,8192,256)
  const float* W_attn = (const float*)d_in[3];  // (256,512)
  const float* b_attn = (const float*)d_in[4];  // (256,)
  const float* vvec = (const float*)d_in[5];    // (256,)

  float* out = (float*)d_out;
  float* ctx = out;          // 16*256 (qb scratch, then final context)
  float* attn = out + 4096;  // 16*8192 (raw scores -> weights in place)
  float* ctxp = (float*)d_ws;            // 512*256 per-block partial contexts
  float* mblk = ctxp + 512 * 256;        // 512 per-block maxes
  float* zblk = mblk + 512;              // 512 per-block partition sums

  prep_kernel<<<dim3(B_SZ, 4), 256, 0, stream>>>(query, W_attn, b_attn, ctx);
  fused_kernel<<<512, 1024, 0, stream>>>(key, value, W_attn, ctx, vvec, attn,
                                         ctxp, mblk, zblk);
  combine_kernel<<<B_SZ, 1024, 0, stream>>>(ctxp, mblk, zblk, attn, ctx);
}